// Round 5
// baseline (184.870 us; speedup 1.0000x reference)
//
#include <hip/hip_runtime.h>
#include <math.h>
#include <stdint.h>

// Problem constants (static per reference)
#define BB 8
#define NN 384
#define FF 64
#define TT 192
#define NSRC 383          // T + TAU - 1
#define NSINK 192
#define SS 5
#define NEDGE 441600      // B * 55200
#define BN (BB * NN)      // 3072
#define TILE_E 128
#define NBLKE (NEDGE / TILE_E)    // 3450 exactly
#define OUTV ((BB * NN * NN) / 4) // 294912 float4 to zero

// ---------------- prep: node projections (4 rows/block) + weight folding ----------------
// blocks 0..767: A[bn][k] = (nodes[bn] @ w1_top)[k] + b1[k];  Bv[bn][k] = (nodes[bn] @ w1_bot)[k]
// block 768: W2kj[k][j] = g1[k]*w2[k][j] (k-major); wcol[j] = sum_k W2kj[k][j]
//            cb[j] = b2[j] + sum_k be1[k]*w2[k][j]
//            gw[j] = g2[j]*w3[j];  cwsgw = {b3 + sum_j be2[j]*w3[j], sum_j gw[j]}
__global__ __launch_bounds__(64) void prep_all(
    const float* __restrict__ nodes, const float* __restrict__ w1,
    const float* __restrict__ b1,
    const float* __restrict__ w2, const float* __restrict__ b2,
    const float* __restrict__ g1, const float* __restrict__ be1,
    const float* __restrict__ g2, const float* __restrict__ be2,
    const float* __restrict__ w3, const float* __restrict__ b3,
    float* __restrict__ A, float* __restrict__ Bv,
    float* __restrict__ W2kj, float* __restrict__ wcol,
    float* __restrict__ cb, float* __restrict__ gw,
    float* __restrict__ cwsgw) {
  const int blk = blockIdx.x;
  const int k = threadIdx.x;
  if (blk < BN / 4) {
    const int bn0 = blk * 4;
    __shared__ float nd[4][FF];
#pragma unroll
    for (int i = 0; i < 4; ++i) nd[i][k] = nodes[(bn0 + i) * FF + k];
    __syncthreads();
    const float bk = b1[k];
    float a0 = bk, a1 = bk, a2 = bk, a3 = bk;
    float q0 = 0.f, q1 = 0.f, q2 = 0.f, q3 = 0.f;
#pragma unroll 8
    for (int f = 0; f < FF; ++f) {
      const float wt = w1[f * FF + k];
      const float wb = w1[(FF + f) * FF + k];
      const float n0 = nd[0][f], n1 = nd[1][f], n2 = nd[2][f], n3 = nd[3][f];
      a0 = fmaf(n0, wt, a0); a1 = fmaf(n1, wt, a1);
      a2 = fmaf(n2, wt, a2); a3 = fmaf(n3, wt, a3);
      q0 = fmaf(n0, wb, q0); q1 = fmaf(n1, wb, q1);
      q2 = fmaf(n2, wb, q2); q3 = fmaf(n3, wb, q3);
    }
    A[(bn0 + 0) * FF + k] = a0;  Bv[(bn0 + 0) * FF + k] = q0;
    A[(bn0 + 1) * FF + k] = a1;  Bv[(bn0 + 1) * FF + k] = q1;
    A[(bn0 + 2) * FF + k] = a2;  Bv[(bn0 + 2) * FF + k] = q2;
    A[(bn0 + 3) * FF + k] = a3;  Bv[(bn0 + 3) * FF + k] = q3;
  } else {
    const int j = k;
    float cbj = b2[j];
    float wc = 0.f;
    for (int kk = 0; kk < FF; ++kk) {
      const float wraw = w2[kk * FF + j];
      const float w = g1[kk] * wraw;
      W2kj[kk * FF + j] = w;
      wc += w;
      cbj = fmaf(be1[kk], wraw, cbj);
    }
    wcol[j] = wc;
    cb[j] = cbj;
    const float gwj = g2[j] * w3[j];
    gw[j] = gwj;
    __shared__ float sA[FF], sB[FF];
    sA[j] = gwj;
    sB[j] = be2[j] * w3[j];
    __syncthreads();
    if (j == 0) {
      float a = 0.f, bq = 0.f;
      for (int i = 0; i < FF; ++i) { a += sA[i]; bq += sB[i]; }
      cwsgw[0] = b3[0] + bq;
      cwsgw[1] = a;
    }
  }
}

// ---------------- main: block-tiled GEMM, 128 edges/block, W2 from L1 ----------------
// threads: 256.  Register tile: 4 edges x 8 j per thread (32 accums).
// thread -> (eg = tid>>3 in [0,32), joct = tid&7 in [0,8))
__global__ __launch_bounds__(256, 4) void edge_mlp(
    const float* __restrict__ A, const float* __restrict__ Bv,
    const float* __restrict__ W2kj, const float* __restrict__ wcolg,
    const float* __restrict__ cbg, const float* __restrict__ gwg,
    const float* __restrict__ cwsgw,
    const int* __restrict__ bidx, const int* __restrict__ ridx,
    const int* __restrict__ cidx, float* __restrict__ L,
    float4* __restrict__ outv) {
  __shared__ float X[FF][TILE_E];    // 32 KB, k-major raw relu(a+b)
  __shared__ float St[TILE_E][2];    // 1 KB, {mu, rstd} per edge

  const int tid = threadIdx.x;
  const int gtid = blockIdx.x * 256 + tid;
  if (gtid < OUTV) outv[gtid] = make_float4(0.f, 0.f, 0.f, 0.f);

  const int e0 = blockIdx.x * TILE_E;

  // ---- phase 1: build X + per-edge LN stats (2 threads per edge) ----
  {
    const int e = tid >> 1;       // 0..127
    const int kh = tid & 1;       // which 32-k half
    const int ge = e0 + e;
    const int b = bidx[ge], r = ridx[ge], c = cidx[ge];
    const float4* pa = (const float4*)(A + (b * NN + r) * FF + kh * 32);
    const float4* pb = (const float4*)(Bv + (b * NN + c) * FF + kh * 32);
    float s = 0.f, q = 0.f;
#pragma unroll
    for (int i = 0; i < 8; ++i) {
      const float4 av = pa[i];
      const float4 bv = pb[i];
      const float x0 = fmaxf(av.x + bv.x, 0.f);
      const float x1 = fmaxf(av.y + bv.y, 0.f);
      const float x2 = fmaxf(av.z + bv.z, 0.f);
      const float x3 = fmaxf(av.w + bv.w, 0.f);
      const int kb = kh * 32 + 4 * i;
      X[kb + 0][e] = x0; X[kb + 1][e] = x1;
      X[kb + 2][e] = x2; X[kb + 3][e] = x3;
      s += x0; s += x1; s += x2; s += x3;
      q = fmaf(x0, x0, q); q = fmaf(x1, x1, q);
      q = fmaf(x2, x2, q); q = fmaf(x3, x3, q);
    }
    // combine the two halves (lanes 2e, 2e+1 adjacent in-wave)
    s += __shfl_xor(s, 1, 64);
    q += __shfl_xor(q, 1, 64);
    const float mu = s * (1.f / FF);
    const float rstd = 1.f / sqrtf(q * (1.f / FF) - mu * mu + 1e-5f);
    St[e][kh] = kh ? rstd : mu;
  }

  // ---- per-thread j-range constants (tiny tables, L1-hot) ----
  const int joct = tid & 7;
  const int eg = tid >> 3;
  float wc[8], cbv[8], gwv[8];
  *(float4*)&wc[0] = *(const float4*)(wcolg + 8 * joct);
  *(float4*)&wc[4] = *(const float4*)(wcolg + 8 * joct + 4);
  *(float4*)&cbv[0] = *(const float4*)(cbg + 8 * joct);
  *(float4*)&cbv[4] = *(const float4*)(cbg + 8 * joct + 4);
  *(float4*)&gwv[0] = *(const float4*)(gwg + 8 * joct);
  *(float4*)&gwv[4] = *(const float4*)(gwg + 8 * joct + 4);
  const float cw = cwsgw[0], sgw = cwsgw[1];

  __syncthreads();

  // ---- phase 2: k-loop GEMM, 4 edges x 8 j per thread; W from L1 ----
  float t[4][8];
#pragma unroll
  for (int ei = 0; ei < 4; ++ei)
#pragma unroll
    for (int jj = 0; jj < 8; ++jj) t[ei][jj] = 0.f;

  const float4* __restrict__ wp = (const float4*)(W2kj + 8 * joct);
#pragma unroll 8
  for (int k = 0; k < FF; ++k) {
    const float4 x4 = *(const float4*)&X[k][4 * eg];
    const float4 w0 = wp[0];
    const float4 w1v = wp[1];
    wp += FF / 4;
    const float w[8] = {w0.x, w0.y, w0.z, w0.w, w1v.x, w1v.y, w1v.z, w1v.w};
    const float xe[4] = {x4.x, x4.y, x4.z, x4.w};
#pragma unroll
    for (int ei = 0; ei < 4; ++ei)
#pragma unroll
      for (int jj = 0; jj < 8; ++jj)
        t[ei][jj] = fmaf(xe[ei], w[jj], t[ei][jj]);
  }

  // ---- epilogue: LN1-affine + relu + LN2 stats, reduce over joct lanes ----
  float mu_[4], rs_[4];
#pragma unroll
  for (int ei = 0; ei < 4; ++ei) {
    mu_[ei] = St[4 * eg + ei][0];
    rs_[ei] = St[4 * eg + ei][1];
  }
  float s1[4], s2[4], s3[4];
#pragma unroll
  for (int ei = 0; ei < 4; ++ei) { s1[ei] = 0.f; s2[ei] = 0.f; s3[ei] = 0.f; }
#pragma unroll
  for (int ei = 0; ei < 4; ++ei) {
#pragma unroll
    for (int jj = 0; jj < 8; ++jj) {
      const float pre = fmaf(rs_[ei], fmaf(-mu_[ei], wc[jj], t[ei][jj]), cbv[jj]);
      const float tr = fmaxf(pre, 0.f);
      s1[ei] += tr;
      s2[ei] = fmaf(tr, tr, s2[ei]);
      s3[ei] = fmaf(tr, gwv[jj], s3[ei]);
    }
  }
#pragma unroll
  for (int off = 1; off <= 4; off <<= 1) {
#pragma unroll
    for (int ei = 0; ei < 4; ++ei) {
      s1[ei] += __shfl_xor(s1[ei], off, 64);
      s2[ei] += __shfl_xor(s2[ei], off, 64);
      s3[ei] += __shfl_xor(s3[ei], off, 64);
    }
  }
  if (joct < 4) {
    const int ei = joct;
    const int ge = e0 + 4 * eg + ei;
    const int b = bidx[ge], r = ridx[ge], c = cidx[ge];
    const float mu2 = s1[ei] * (1.f / FF);
    const float var2 = s2[ei] * (1.f / FF) - mu2 * mu2;
    const float rstd2 = 1.f / sqrtf(var2 + 1e-5f);
    const float logit = fmaf(rstd2, fmaf(-mu2, sgw, s3[ei]), cw);
    L[(b * NSINK + (r - TT)) * NSRC + c] = logit;
  }
}

// ---------------- argmax over sources + scatter ones ----------------
__global__ __launch_bounds__(256) void argmax_scatter(
    const float* __restrict__ L, const float* __restrict__ gum,
    float* __restrict__ out) {
  const int task = blockIdx.x * 4 + (threadIdx.x >> 6);  // ((s*B+b)*192+row)
  const int lane = threadIdx.x & 63;
  const int row = task % NSINK;
  const int sb = task / NSINK;   // s*B + b
  const int b = sb & 7;
  const int r = row + TT;

  const float* __restrict__ lrow = L + (b * NSINK + row) * NSRC;
  const float* __restrict__ grow = gum + task * NSRC;

  float bv = -INFINITY;
  int bi = 0;
  for (int c = lane; c < r; c += 64) {
    const float v = lrow[c] + grow[c];
    if (v > bv) { bv = v; bi = c; }   // strict > keeps smallest index per lane
  }
#pragma unroll
  for (int off = 32; off > 0; off >>= 1) {
    const float ov = __shfl_xor(bv, off, 64);
    const int oi = __shfl_xor(bi, off, 64);
    if (ov > bv || (ov == bv && oi < bi)) { bv = ov; bi = oi; }
  }
  if (lane == 0) out[(b * NN + r) * NN + bi] = 1.0f;
}

extern "C" void kernel_launch(void* const* d_in, const int* in_sizes, int n_in,
                              void* d_out, int out_size, void* d_ws, size_t ws_size,
                              hipStream_t stream) {
  const float* nodes = (const float*)d_in[0];
  const float* w1 = (const float*)d_in[1];
  const float* b1 = (const float*)d_in[2];
  const float* g1 = (const float*)d_in[3];
  const float* be1 = (const float*)d_in[4];
  const float* w2 = (const float*)d_in[5];
  const float* b2 = (const float*)d_in[6];
  const float* g2 = (const float*)d_in[7];
  const float* be2 = (const float*)d_in[8];
  const float* w3 = (const float*)d_in[9];
  const float* b3 = (const float*)d_in[10];
  const float* gum = (const float*)d_in[11];
  const int* bidx = (const int*)d_in[12];
  const int* ridx = (const int*)d_in[13];
  const int* cidx = (const int*)d_in[14];
  float* out = (float*)d_out;

  // workspace layout (floats)
  float* ws = (float*)d_ws;
  float* A = ws;                       // 8*384*64 = 196608
  float* Bv = A + BN * FF;             // 196608
  float* W2kj = Bv + BN * FF;          // 4096
  float* wcol = W2kj + FF * FF;        // 64
  float* cb = wcol + FF;               // 64
  float* gw = cb + FF;                 // 64
  float* cwsgw = gw + FF;              // 2
  float* L = ws + 397520;              // 8*192*383 = 588288
  (void)ws_size; (void)n_in; (void)in_sizes; (void)out_size;

  hipLaunchKernelGGL(prep_all, dim3(BN / 4 + 1), dim3(64), 0, stream,
                     nodes, w1, b1, w2, b2, g1, be1, g2, be2, w3, b3,
                     A, Bv, W2kj, wcol, cb, gw, cwsgw);
  hipLaunchKernelGGL(edge_mlp, dim3(NBLKE), dim3(256), 0, stream,
                     A, Bv, W2kj, wcol, cb, gw, cwsgw, bidx, ridx, cidx, L,
                     (float4*)out);
  hipLaunchKernelGGL(argmax_scatter, dim3((SS * BB * NSINK) / 4), dim3(256), 0, stream,
                     L, gum, out);
}

// Round 6
// 156.873 us; speedup vs baseline: 1.1785x; 1.1785x over previous
//
#include <hip/hip_runtime.h>
#include <math.h>
#include <stdint.h>

// Problem constants (static per reference)
#define BB 8
#define NN 384
#define FF 64
#define TT 192
#define NSRC 383          // T + TAU - 1
#define NSINK 192
#define SS 5
#define NEDGE 441600      // B * 55200
#define BN (BB * NN)      // 3072
#define TILE_E 128
#define NBLKE (NEDGE / TILE_E)    // 3450 exactly
#define OUTV ((BB * NN * NN) / 4) // 294912 float4 to zero

// ---------------- prep: node projections (4 rows/block) + weight folding ----------------
__global__ __launch_bounds__(64) void prep_all(
    const float* __restrict__ nodes, const float* __restrict__ w1,
    const float* __restrict__ b1,
    const float* __restrict__ w2, const float* __restrict__ b2,
    const float* __restrict__ g1, const float* __restrict__ be1,
    const float* __restrict__ g2, const float* __restrict__ be2,
    const float* __restrict__ w3, const float* __restrict__ b3,
    float* __restrict__ A, float* __restrict__ Bv,
    float* __restrict__ W2kj, float* __restrict__ wcol,
    float* __restrict__ cb, float* __restrict__ gw,
    float* __restrict__ cwsgw) {
  const int blk = blockIdx.x;
  const int k = threadIdx.x;
  if (blk < BN / 4) {
    const int bn0 = blk * 4;
    __shared__ float nd[4][FF];
#pragma unroll
    for (int i = 0; i < 4; ++i) nd[i][k] = nodes[(bn0 + i) * FF + k];
    __syncthreads();
    const float bk = b1[k];
    float a0 = bk, a1 = bk, a2 = bk, a3 = bk;
    float q0 = 0.f, q1 = 0.f, q2 = 0.f, q3 = 0.f;
#pragma unroll 8
    for (int f = 0; f < FF; ++f) {
      const float wt = w1[f * FF + k];
      const float wb = w1[(FF + f) * FF + k];
      const float n0 = nd[0][f], n1 = nd[1][f], n2 = nd[2][f], n3 = nd[3][f];
      a0 = fmaf(n0, wt, a0); a1 = fmaf(n1, wt, a1);
      a2 = fmaf(n2, wt, a2); a3 = fmaf(n3, wt, a3);
      q0 = fmaf(n0, wb, q0); q1 = fmaf(n1, wb, q1);
      q2 = fmaf(n2, wb, q2); q3 = fmaf(n3, wb, q3);
    }
    A[(bn0 + 0) * FF + k] = a0;  Bv[(bn0 + 0) * FF + k] = q0;
    A[(bn0 + 1) * FF + k] = a1;  Bv[(bn0 + 1) * FF + k] = q1;
    A[(bn0 + 2) * FF + k] = a2;  Bv[(bn0 + 2) * FF + k] = q2;
    A[(bn0 + 3) * FF + k] = a3;  Bv[(bn0 + 3) * FF + k] = q3;
  } else {
    const int j = k;
    float cbj = b2[j];
    float wc = 0.f;
    for (int kk = 0; kk < FF; ++kk) {
      const float wraw = w2[kk * FF + j];
      const float w = g1[kk] * wraw;
      W2kj[kk * FF + j] = w;
      wc += w;
      cbj = fmaf(be1[kk], wraw, cbj);
    }
    wcol[j] = wc;
    cb[j] = cbj;
    const float gwj = g2[j] * w3[j];
    gw[j] = gwj;
    __shared__ float sA[FF], sB[FF];
    sA[j] = gwj;
    sB[j] = be2[j] * w3[j];
    __syncthreads();
    if (j == 0) {
      float a = 0.f, bq = 0.f;
      for (int i = 0; i < FF; ++i) { a += sA[i]; bq += sB[i]; }
      cwsgw[0] = b3[0] + bq;
      cwsgw[1] = a;
    }
  }
}

// ---------------- main: wave-autonomous tiled GEMM, 32 edges/wave ----------------
// 256 threads = 4 waves; each wave owns a private X slab (no per-tile barrier).
// One block-wide barrier only after the one-time W2 staging.
// lane -> (egs = lane>>3 in [0,8) : edge-quad, joct = lane&7 : j-octet)
__global__ __launch_bounds__(256, 4) void edge_mlp(
    const float* __restrict__ A, const float* __restrict__ Bv,
    const float* __restrict__ W2kj, const float* __restrict__ wcolg,
    const float* __restrict__ cbg, const float* __restrict__ gwg,
    const float* __restrict__ cwsgw,
    const int* __restrict__ bidx, const int* __restrict__ ridx,
    const int* __restrict__ cidx, float* __restrict__ L,
    float4* __restrict__ outv) {
  __shared__ float Wl[FF][FF];        // 16 KB, k-major, block-shared
  __shared__ float X[4][FF][32];      // 32 KB, wave-private k-major slabs
  __shared__ float St[4][32][2];      // 1 KB, wave-private {mu, rstd}

  const int tid = threadIdx.x;
  const int wave = tid >> 6;
  const int lane = tid & 63;
  const int gtid = blockIdx.x * 256 + tid;
  if (gtid < OUTV) outv[gtid] = make_float4(0.f, 0.f, 0.f, 0.f);

  const int e0 = blockIdx.x * TILE_E + wave * 32;

  // ---- one-time W2 staging (coalesced float4), then the ONLY barrier ----
  {
    const float4* src = (const float4*)W2kj;
    float4* dst = (float4*)&Wl[0][0];
#pragma unroll
    for (int i = 0; i < 4; ++i) dst[tid + 256 * i] = src[tid + 256 * i];
  }

  // per-thread j-range constants: issue early, they drain at the barrier
  const int joct = lane & 7;
  const int egs = lane >> 3;
  float wc[8], cbv[8], gwv[8];
  *(float4*)&wc[0] = *(const float4*)(wcolg + 8 * joct);
  *(float4*)&wc[4] = *(const float4*)(wcolg + 8 * joct + 4);
  *(float4*)&cbv[0] = *(const float4*)(cbg + 8 * joct);
  *(float4*)&cbv[4] = *(const float4*)(cbg + 8 * joct + 4);
  *(float4*)&gwv[0] = *(const float4*)(gwg + 8 * joct);
  *(float4*)&gwv[4] = *(const float4*)(gwg + 8 * joct + 4);
  const float cw = cwsgw[0], sgw = cwsgw[1];

  __syncthreads();

  // ---- phase 1 (wave-local): build X slab + per-edge LN stats ----
  {
    const int e = lane >> 1;       // 0..31 local edge
    const int kh = lane & 1;       // which 32-k half
    const int ge = e0 + e;
    const int b = bidx[ge], r = ridx[ge], c = cidx[ge];
    const float4* pa = (const float4*)(A + (b * NN + r) * FF + kh * 32);
    const float4* pb = (const float4*)(Bv + (b * NN + c) * FF + kh * 32);
    float s = 0.f, q = 0.f;
#pragma unroll
    for (int i = 0; i < 8; ++i) {
      const float4 av = pa[i];
      const float4 bv = pb[i];
      const float x0 = fmaxf(av.x + bv.x, 0.f);
      const float x1 = fmaxf(av.y + bv.y, 0.f);
      const float x2 = fmaxf(av.z + bv.z, 0.f);
      const float x3 = fmaxf(av.w + bv.w, 0.f);
      const int kb = kh * 32 + 4 * i;
      X[wave][kb + 0][e] = x0; X[wave][kb + 1][e] = x1;
      X[wave][kb + 2][e] = x2; X[wave][kb + 3][e] = x3;
      s += x0; s += x1; s += x2; s += x3;
      q = fmaf(x0, x0, q); q = fmaf(x1, x1, q);
      q = fmaf(x2, x2, q); q = fmaf(x3, x3, q);
    }
    // lanes 2e, 2e+1 hold the two k-halves of edge e
    s += __shfl_xor(s, 1, 64);
    q += __shfl_xor(q, 1, 64);
    const float mu = s * (1.f / FF);
    const float rstd = 1.f / sqrtf(q * (1.f / FF) - mu * mu + 1e-5f);
    St[wave][e][kh] = kh ? rstd : mu;
  }
  // wave-local LDS RAW: DS pipe is in-order per wave; fence compiler reordering
  __builtin_amdgcn_wave_barrier();

  // ---- phase 2: k-loop GEMM, 4 edges x 8 j per lane, all LDS-fed ----
  float t[4][8];
#pragma unroll
  for (int ei = 0; ei < 4; ++ei)
#pragma unroll
    for (int jj = 0; jj < 8; ++jj) t[ei][jj] = 0.f;

  const float* xp = &X[wave][0][4 * egs];   // +32 floats per k
  const float* wp = &Wl[0][8 * joct];       // +64 floats per k
#pragma unroll 8
  for (int k = 0; k < FF; ++k) {
    const float4 x4 = *(const float4*)xp;  xp += 32;
    const float4 w0 = *(const float4*)wp;
    const float4 w1v = *(const float4*)(wp + 4);  wp += 64;
    const float w[8] = {w0.x, w0.y, w0.z, w0.w, w1v.x, w1v.y, w1v.z, w1v.w};
    const float xe[4] = {x4.x, x4.y, x4.z, x4.w};
#pragma unroll
    for (int ei = 0; ei < 4; ++ei)
#pragma unroll
      for (int jj = 0; jj < 8; ++jj)
        t[ei][jj] = fmaf(xe[ei], w[jj], t[ei][jj]);
  }

  // ---- epilogue: LN1-affine + relu + LN2 stats, reduce over joct lanes ----
  float mu_[4], rs_[4];
#pragma unroll
  for (int ei = 0; ei < 4; ++ei) {
    mu_[ei] = St[wave][4 * egs + ei][0];
    rs_[ei] = St[wave][4 * egs + ei][1];
  }
  float s1[4], s2[4], s3[4];
#pragma unroll
  for (int ei = 0; ei < 4; ++ei) { s1[ei] = 0.f; s2[ei] = 0.f; s3[ei] = 0.f; }
#pragma unroll
  for (int ei = 0; ei < 4; ++ei) {
#pragma unroll
    for (int jj = 0; jj < 8; ++jj) {
      const float pre = fmaf(rs_[ei], fmaf(-mu_[ei], wc[jj], t[ei][jj]), cbv[jj]);
      const float tr = fmaxf(pre, 0.f);
      s1[ei] += tr;
      s2[ei] = fmaf(tr, tr, s2[ei]);
      s3[ei] = fmaf(tr, gwv[jj], s3[ei]);
    }
  }
#pragma unroll
  for (int off = 1; off <= 4; off <<= 1) {
#pragma unroll
    for (int ei = 0; ei < 4; ++ei) {
      s1[ei] += __shfl_xor(s1[ei], off, 64);
      s2[ei] += __shfl_xor(s2[ei], off, 64);
      s3[ei] += __shfl_xor(s3[ei], off, 64);
    }
  }
  if (joct < 4) {
    const int ei = joct;
    const int ge = e0 + 4 * egs + ei;
    const int b = bidx[ge], r = ridx[ge], c = cidx[ge];
    const float mu2 = s1[ei] * (1.f / FF);
    const float var2 = s2[ei] * (1.f / FF) - mu2 * mu2;
    const float rstd2 = 1.f / sqrtf(var2 + 1e-5f);
    const float logit = fmaf(rstd2, fmaf(-mu2, sgw, s3[ei]), cw);
    L[(b * NSINK + (r - TT)) * NSRC + c] = logit;
  }
}

// ---------------- argmax over sources + scatter ones ----------------
__global__ __launch_bounds__(256) void argmax_scatter(
    const float* __restrict__ L, const float* __restrict__ gum,
    float* __restrict__ out) {
  const int task = blockIdx.x * 4 + (threadIdx.x >> 6);  // ((s*B+b)*192+row)
  const int lane = threadIdx.x & 63;
  const int row = task % NSINK;
  const int sb = task / NSINK;   // s*B + b
  const int b = sb & 7;
  const int r = row + TT;

  const float* __restrict__ lrow = L + (b * NSINK + row) * NSRC;
  const float* __restrict__ grow = gum + task * NSRC;

  float bv = -INFINITY;
  int bi = 0;
  for (int c = lane; c < r; c += 64) {
    const float v = lrow[c] + grow[c];
    if (v > bv) { bv = v; bi = c; }   // strict > keeps smallest index per lane
  }
#pragma unroll
  for (int off = 32; off > 0; off >>= 1) {
    const float ov = __shfl_xor(bv, off, 64);
    const int oi = __shfl_xor(bi, off, 64);
    if (ov > bv || (ov == bv && oi < bi)) { bv = ov; bi = oi; }
  }
  if (lane == 0) out[(b * NN + r) * NN + bi] = 1.0f;
}

extern "C" void kernel_launch(void* const* d_in, const int* in_sizes, int n_in,
                              void* d_out, int out_size, void* d_ws, size_t ws_size,
                              hipStream_t stream) {
  const float* nodes = (const float*)d_in[0];
  const float* w1 = (const float*)d_in[1];
  const float* b1 = (const float*)d_in[2];
  const float* g1 = (const float*)d_in[3];
  const float* be1 = (const float*)d_in[4];
  const float* w2 = (const float*)d_in[5];
  const float* b2 = (const float*)d_in[6];
  const float* g2 = (const float*)d_in[7];
  const float* be2 = (const float*)d_in[8];
  const float* w3 = (const float*)d_in[9];
  const float* b3 = (const float*)d_in[10];
  const float* gum = (const float*)d_in[11];
  const int* bidx = (const int*)d_in[12];
  const int* ridx = (const int*)d_in[13];
  const int* cidx = (const int*)d_in[14];
  float* out = (float*)d_out;

  // workspace layout (floats)
  float* ws = (float*)d_ws;
  float* A = ws;                       // 8*384*64 = 196608
  float* Bv = A + BN * FF;             // 196608
  float* W2kj = Bv + BN * FF;          // 4096
  float* wcol = W2kj + FF * FF;        // 64
  float* cb = wcol + FF;               // 64
  float* gw = cb + FF;                 // 64
  float* cwsgw = gw + FF;              // 2
  float* L = ws + 397520;              // 8*192*383 = 588288
  (void)ws_size; (void)n_in; (void)in_sizes; (void)out_size;

  hipLaunchKernelGGL(prep_all, dim3(BN / 4 + 1), dim3(64), 0, stream,
                     nodes, w1, b1, w2, b2, g1, be1, g2, be2, w3, b3,
                     A, Bv, W2kj, wcol, cb, gw, cwsgw);
  hipLaunchKernelGGL(edge_mlp, dim3(NBLKE), dim3(256), 0, stream,
                     A, Bv, W2kj, wcol, cb, gw, cwsgw, bidx, ridx, cidx, L,
                     (float4*)out);
  hipLaunchKernelGGL(argmax_scatter, dim3((SS * BB * NSINK) / 4), dim3(256), 0, stream,
                     L, gum, out);
}

// Round 7
// 155.751 us; speedup vs baseline: 1.1870x; 1.0072x over previous
//
#include <hip/hip_runtime.h>
#include <math.h>
#include <stdint.h>

// Problem constants (static per reference)
#define BB 8
#define NN 384
#define FF 64
#define TT 192
#define NSRC 383          // T + TAU - 1
#define NSINK 192
#define SS 5
#define NEDGE 441600      // B * 55200
#define BN (BB * NN)      // 3072
#define TILE_E 128
#define NBLKE (NEDGE / TILE_E)    // 3450 exactly
#define OUTV ((BB * NN * NN) / 4) // 294912 float4 to zero

typedef float f32x2 __attribute__((ext_vector_type(2)));

#if defined(__has_builtin) && __has_builtin(__builtin_elementwise_fma)
#define PKFMA(a, b, c) __builtin_elementwise_fma((a), (b), (c))
#else
#define PKFMA(a, b, c) ((a) * (b) + (c))   // -ffp-contract=fast contracts this
#endif

// ---------------- prep: node projections (4 rows/block) + weight folding ----------------
__global__ __launch_bounds__(64) void prep_all(
    const float* __restrict__ nodes, const float* __restrict__ w1,
    const float* __restrict__ b1,
    const float* __restrict__ w2, const float* __restrict__ b2,
    const float* __restrict__ g1, const float* __restrict__ be1,
    const float* __restrict__ g2, const float* __restrict__ be2,
    const float* __restrict__ w3, const float* __restrict__ b3,
    float* __restrict__ A, float* __restrict__ Bv,
    float* __restrict__ W2kj, float* __restrict__ wcol,
    float* __restrict__ cb, float* __restrict__ gw,
    float* __restrict__ cwsgw) {
  const int blk = blockIdx.x;
  const int k = threadIdx.x;
  if (blk < BN / 4) {
    const int bn0 = blk * 4;
    __shared__ float nd[4][FF];
#pragma unroll
    for (int i = 0; i < 4; ++i) nd[i][k] = nodes[(bn0 + i) * FF + k];
    __syncthreads();
    const float bk = b1[k];
    float a0 = bk, a1 = bk, a2 = bk, a3 = bk;
    float q0 = 0.f, q1 = 0.f, q2 = 0.f, q3 = 0.f;
#pragma unroll 8
    for (int f = 0; f < FF; ++f) {
      const float wt = w1[f * FF + k];
      const float wb = w1[(FF + f) * FF + k];
      const float n0 = nd[0][f], n1 = nd[1][f], n2 = nd[2][f], n3 = nd[3][f];
      a0 = fmaf(n0, wt, a0); a1 = fmaf(n1, wt, a1);
      a2 = fmaf(n2, wt, a2); a3 = fmaf(n3, wt, a3);
      q0 = fmaf(n0, wb, q0); q1 = fmaf(n1, wb, q1);
      q2 = fmaf(n2, wb, q2); q3 = fmaf(n3, wb, q3);
    }
    A[(bn0 + 0) * FF + k] = a0;  Bv[(bn0 + 0) * FF + k] = q0;
    A[(bn0 + 1) * FF + k] = a1;  Bv[(bn0 + 1) * FF + k] = q1;
    A[(bn0 + 2) * FF + k] = a2;  Bv[(bn0 + 2) * FF + k] = q2;
    A[(bn0 + 3) * FF + k] = a3;  Bv[(bn0 + 3) * FF + k] = q3;
  } else {
    const int j = k;
    float cbj = b2[j];
    float wc = 0.f;
    for (int kk = 0; kk < FF; ++kk) {
      const float wraw = w2[kk * FF + j];
      const float w = g1[kk] * wraw;
      W2kj[kk * FF + j] = w;
      wc += w;
      cbj = fmaf(be1[kk], wraw, cbj);
    }
    wcol[j] = wc;
    cb[j] = cbj;
    const float gwj = g2[j] * w3[j];
    gw[j] = gwj;
    __shared__ float sA[FF], sB[FF];
    sA[j] = gwj;
    sB[j] = be2[j] * w3[j];
    __syncthreads();
    if (j == 0) {
      float a = 0.f, bq = 0.f;
      for (int i = 0; i < FF; ++i) { a += sA[i]; bq += sB[i]; }
      cwsgw[0] = b3[0] + bq;
      cwsgw[1] = a;
    }
  }
}

// ---------------- main: wave-autonomous tiled GEMM, packed-fp32 inner loop ----------------
// 256 threads = 4 waves; each wave owns a private X slab.
// lane -> (egs = lane>>3 : edge-quad, joct = lane&7 : j-octet)
__global__ __launch_bounds__(256, 4) void edge_mlp(
    const float* __restrict__ A, const float* __restrict__ Bv,
    const float* __restrict__ W2kj, const float* __restrict__ wcolg,
    const float* __restrict__ cbg, const float* __restrict__ gwg,
    const float* __restrict__ cwsgw,
    const int* __restrict__ bidx, const int* __restrict__ ridx,
    const int* __restrict__ cidx, float* __restrict__ L,
    float4* __restrict__ outv) {
  __shared__ float Wl[FF][FF];        // 16 KB, k-major, block-shared
  __shared__ float X[4][FF][32];      // 32 KB, wave-private k-major slabs
  __shared__ float St[4][32][2];      // 1 KB, wave-private {mu, rstd}

  const int tid = threadIdx.x;
  const int wave = tid >> 6;
  const int lane = tid & 63;
  const int gtid = blockIdx.x * 256 + tid;
  if (gtid < OUTV) outv[gtid] = make_float4(0.f, 0.f, 0.f, 0.f);

  const int e0 = blockIdx.x * TILE_E + wave * 32;

  // ---- one-time W2 staging (coalesced float4), then the ONLY barrier ----
  {
    const float4* src = (const float4*)W2kj;
    float4* dst = (float4*)&Wl[0][0];
#pragma unroll
    for (int i = 0; i < 4; ++i) dst[tid + 256 * i] = src[tid + 256 * i];
  }

  const int joct = lane & 7;
  const int egs = lane >> 3;
  float wc[8], cbv[8], gwv[8];
  *(float4*)&wc[0] = *(const float4*)(wcolg + 8 * joct);
  *(float4*)&wc[4] = *(const float4*)(wcolg + 8 * joct + 4);
  *(float4*)&cbv[0] = *(const float4*)(cbg + 8 * joct);
  *(float4*)&cbv[4] = *(const float4*)(cbg + 8 * joct + 4);
  *(float4*)&gwv[0] = *(const float4*)(gwg + 8 * joct);
  *(float4*)&gwv[4] = *(const float4*)(gwg + 8 * joct + 4);
  const float cw = cwsgw[0], sgw = cwsgw[1];

  __syncthreads();

  // ---- phase 1 (wave-local): build X slab + per-edge LN stats ----
  {
    const int e = lane >> 1;       // 0..31 local edge
    const int kh = lane & 1;       // which 32-k half
    const int ge = e0 + e;
    const int b = bidx[ge], r = ridx[ge], c = cidx[ge];
    const float4* pa = (const float4*)(A + (b * NN + r) * FF + kh * 32);
    const float4* pb = (const float4*)(Bv + (b * NN + c) * FF + kh * 32);
    float s = 0.f, q = 0.f;
#pragma unroll
    for (int i = 0; i < 8; ++i) {
      const float4 av = pa[i];
      const float4 bv = pb[i];
      const float x0 = fmaxf(av.x + bv.x, 0.f);
      const float x1 = fmaxf(av.y + bv.y, 0.f);
      const float x2 = fmaxf(av.z + bv.z, 0.f);
      const float x3 = fmaxf(av.w + bv.w, 0.f);
      const int kb = kh * 32 + 4 * i;
      X[wave][kb + 0][e] = x0; X[wave][kb + 1][e] = x1;
      X[wave][kb + 2][e] = x2; X[wave][kb + 3][e] = x3;
      s += x0; s += x1; s += x2; s += x3;
      q = fmaf(x0, x0, q); q = fmaf(x1, x1, q);
      q = fmaf(x2, x2, q); q = fmaf(x3, x3, q);
    }
    s += __shfl_xor(s, 1, 64);
    q += __shfl_xor(q, 1, 64);
    const float mu = s * (1.f / FF);
    const float rstd = 1.f / sqrtf(q * (1.f / FF) - mu * mu + 1e-5f);
    St[wave][e][kh] = kh ? rstd : mu;
  }
  __builtin_amdgcn_wave_barrier();   // wave-local LDS RAW ordering fence

  // ---- phase 2: k-loop GEMM, 4 edges x 8 j per lane, packed f32x2 ----
  f32x2 t2[4][4];
#pragma unroll
  for (int ei = 0; ei < 4; ++ei)
#pragma unroll
    for (int p = 0; p < 4; ++p) t2[ei][p] = (f32x2){0.f, 0.f};

  const float* xp = &X[wave][0][4 * egs];   // +32 floats per k
  const float* wp = &Wl[0][8 * joct];       // +64 floats per k
#pragma unroll 8
  for (int k = 0; k < FF; ++k) {
    const float4 x4 = *(const float4*)xp;  xp += 32;
    const float4 wA = *(const float4*)wp;
    const float4 wB = *(const float4*)(wp + 4);  wp += 64;
    f32x2 w01; w01.x = wA.x; w01.y = wA.y;
    f32x2 w23; w23.x = wA.z; w23.y = wA.w;
    f32x2 w45; w45.x = wB.x; w45.y = wB.y;
    f32x2 w67; w67.x = wB.z; w67.y = wB.w;
    const float xe[4] = {x4.x, x4.y, x4.z, x4.w};
#pragma unroll
    for (int ei = 0; ei < 4; ++ei) {
      const float xs = xe[ei];
      f32x2 xb; xb.x = xs; xb.y = xs;
      t2[ei][0] = PKFMA(xb, w01, t2[ei][0]);
      t2[ei][1] = PKFMA(xb, w23, t2[ei][1]);
      t2[ei][2] = PKFMA(xb, w45, t2[ei][2]);
      t2[ei][3] = PKFMA(xb, w67, t2[ei][3]);
    }
  }

  // ---- epilogue: LN1-affine + relu + LN2 stats, reduce over joct lanes ----
  float mu_[4], rs_[4];
#pragma unroll
  for (int ei = 0; ei < 4; ++ei) {
    mu_[ei] = St[wave][4 * egs + ei][0];
    rs_[ei] = St[wave][4 * egs + ei][1];
  }
  float s1[4], s2[4], s3[4];
#pragma unroll
  for (int ei = 0; ei < 4; ++ei) { s1[ei] = 0.f; s2[ei] = 0.f; s3[ei] = 0.f; }
#pragma unroll
  for (int ei = 0; ei < 4; ++ei) {
#pragma unroll
    for (int jj = 0; jj < 8; ++jj) {
      const float tv = (jj & 1) ? t2[ei][jj >> 1].y : t2[ei][jj >> 1].x;
      const float pre = fmaf(rs_[ei], fmaf(-mu_[ei], wc[jj], tv), cbv[jj]);
      const float tr = fmaxf(pre, 0.f);
      s1[ei] += tr;
      s2[ei] = fmaf(tr, tr, s2[ei]);
      s3[ei] = fmaf(tr, gwv[jj], s3[ei]);
    }
  }
#pragma unroll
  for (int off = 1; off <= 4; off <<= 1) {
#pragma unroll
    for (int ei = 0; ei < 4; ++ei) {
      s1[ei] += __shfl_xor(s1[ei], off, 64);
      s2[ei] += __shfl_xor(s2[ei], off, 64);
      s3[ei] += __shfl_xor(s3[ei], off, 64);
    }
  }
  if (joct < 4) {
    const int ei = joct;
    const int ge = e0 + 4 * egs + ei;
    const int b = bidx[ge], r = ridx[ge], c = cidx[ge];
    const float mu2 = s1[ei] * (1.f / FF);
    const float var2 = s2[ei] * (1.f / FF) - mu2 * mu2;
    const float rstd2 = 1.f / sqrtf(var2 + 1e-5f);
    const float logit = fmaf(rstd2, fmaf(-mu2, sgw, s3[ei]), cw);
    L[(b * NSINK + (r - TT)) * NSRC + c] = logit;
  }
}

// ---------------- argmax over sources + scatter ones ----------------
__global__ __launch_bounds__(256) void argmax_scatter(
    const float* __restrict__ L, const float* __restrict__ gum,
    float* __restrict__ out) {
  const int task = blockIdx.x * 4 + (threadIdx.x >> 6);  // ((s*B+b)*192+row)
  const int lane = threadIdx.x & 63;
  const int row = task % NSINK;
  const int sb = task / NSINK;   // s*B + b
  const int b = sb & 7;
  const int r = row + TT;

  const float* __restrict__ lrow = L + (b * NSINK + row) * NSRC;
  const float* __restrict__ grow = gum + task * NSRC;

  float bv = -INFINITY;
  int bi = 0;
  for (int c = lane; c < r; c += 64) {
    const float v = lrow[c] + grow[c];
    if (v > bv) { bv = v; bi = c; }   // strict > keeps smallest index per lane
  }
#pragma unroll
  for (int off = 32; off > 0; off >>= 1) {
    const float ov = __shfl_xor(bv, off, 64);
    const int oi = __shfl_xor(bi, off, 64);
    if (ov > bv || (ov == bv && oi < bi)) { bv = ov; bi = oi; }
  }
  if (lane == 0) out[(b * NN + r) * NN + bi] = 1.0f;
}

extern "C" void kernel_launch(void* const* d_in, const int* in_sizes, int n_in,
                              void* d_out, int out_size, void* d_ws, size_t ws_size,
                              hipStream_t stream) {
  const float* nodes = (const float*)d_in[0];
  const float* w1 = (const float*)d_in[1];
  const float* b1 = (const float*)d_in[2];
  const float* g1 = (const float*)d_in[3];
  const float* be1 = (const float*)d_in[4];
  const float* w2 = (const float*)d_in[5];
  const float* b2 = (const float*)d_in[6];
  const float* g2 = (const float*)d_in[7];
  const float* be2 = (const float*)d_in[8];
  const float* w3 = (const float*)d_in[9];
  const float* b3 = (const float*)d_in[10];
  const float* gum = (const float*)d_in[11];
  const int* bidx = (const int*)d_in[12];
  const int* ridx = (const int*)d_in[13];
  const int* cidx = (const int*)d_in[14];
  float* out = (float*)d_out;

  // workspace layout (floats)
  float* ws = (float*)d_ws;
  float* A = ws;                       // 8*384*64 = 196608
  float* Bv = A + BN * FF;             // 196608
  float* W2kj = Bv + BN * FF;          // 4096
  float* wcol = W2kj + FF * FF;        // 64
  float* cb = wcol + FF;               // 64
  float* gw = cb + FF;                 // 64
  float* cwsgw = gw + FF;              // 2
  float* L = ws + 397520;              // 8*192*383 = 588288
  (void)ws_size; (void)n_in; (void)in_sizes; (void)out_size;

  hipLaunchKernelGGL(prep_all, dim3(BN / 4 + 1), dim3(64), 0, stream,
                     nodes, w1, b1, w2, b2, g1, be1, g2, be2, w3, b3,
                     A, Bv, W2kj, wcol, cb, gw, cwsgw);
  hipLaunchKernelGGL(edge_mlp, dim3(NBLKE), dim3(256), 0, stream,
                     A, Bv, W2kj, wcol, cb, gw, cwsgw, bidx, ridx, cidx, L,
                     (float4*)out);
  hipLaunchKernelGGL(argmax_scatter, dim3((SS * BB * NSINK) / 4), dim3(256), 0, stream,
                     L, gum, out);
}

// Round 9
// 153.626 us; speedup vs baseline: 1.2034x; 1.0138x over previous
//
#include <hip/hip_runtime.h>
#include <math.h>
#include <stdint.h>

// Problem constants (static per reference)
#define BB 8
#define NN 384
#define FF 64
#define TT 192
#define NSRC 383          // T + TAU - 1
#define NSINK 192
#define SS 5
#define NEDGE 441600      // B * 55200
#define BN (BB * NN)      // 3072
#define TILE_E 256        // edges per block (4 waves x 64)
#define NBLKE (NEDGE / TILE_E)    // 1725 exactly
#define OUTV ((BB * NN * NN) / 4) // 294912 float4 to zero

typedef float f32x2 __attribute__((ext_vector_type(2)));

#if defined(__has_builtin) && __has_builtin(__builtin_elementwise_fma)
#define PKFMA(a, b, c) __builtin_elementwise_fma((a), (b), (c))
#else
#define PKFMA(a, b, c) ((a) * (b) + (c))
#endif

__device__ __forceinline__ float sel8(const float* s, int i) {
  return (i & 4) ? ((i & 2) ? ((i & 1) ? s[7] : s[6]) : ((i & 1) ? s[5] : s[4]))
                 : ((i & 2) ? ((i & 1) ? s[3] : s[2]) : ((i & 1) ? s[1] : s[0]));
}

// ---------------- prep: node projections (4 rows/block) + weight folding ----------------
__global__ __launch_bounds__(64) void prep_all(
    const float* __restrict__ nodes, const float* __restrict__ w1,
    const float* __restrict__ b1,
    const float* __restrict__ w2, const float* __restrict__ b2,
    const float* __restrict__ g1, const float* __restrict__ be1,
    const float* __restrict__ g2, const float* __restrict__ be2,
    const float* __restrict__ w3, const float* __restrict__ b3,
    float* __restrict__ A, float* __restrict__ Bv,
    float* __restrict__ W2kj, float* __restrict__ wcol,
    float* __restrict__ cb, float* __restrict__ gw,
    float* __restrict__ cwsgw) {
  const int blk = blockIdx.x;
  const int k = threadIdx.x;
  if (blk < BN / 4) {
    const int bn0 = blk * 4;
    __shared__ float nd[4][FF];
#pragma unroll
    for (int i = 0; i < 4; ++i) nd[i][k] = nodes[(bn0 + i) * FF + k];
    __syncthreads();
    const float bk = b1[k];
    float a0 = bk, a1 = bk, a2 = bk, a3 = bk;
    float q0 = 0.f, q1 = 0.f, q2 = 0.f, q3 = 0.f;
#pragma unroll 8
    for (int f = 0; f < FF; ++f) {
      const float wt = w1[f * FF + k];
      const float wb = w1[(FF + f) * FF + k];
      const float n0 = nd[0][f], n1 = nd[1][f], n2 = nd[2][f], n3 = nd[3][f];
      a0 = fmaf(n0, wt, a0); a1 = fmaf(n1, wt, a1);
      a2 = fmaf(n2, wt, a2); a3 = fmaf(n3, wt, a3);
      q0 = fmaf(n0, wb, q0); q1 = fmaf(n1, wb, q1);
      q2 = fmaf(n2, wb, q2); q3 = fmaf(n3, wb, q3);
    }
    A[(bn0 + 0) * FF + k] = a0;  Bv[(bn0 + 0) * FF + k] = q0;
    A[(bn0 + 1) * FF + k] = a1;  Bv[(bn0 + 1) * FF + k] = q1;
    A[(bn0 + 2) * FF + k] = a2;  Bv[(bn0 + 2) * FF + k] = q2;
    A[(bn0 + 3) * FF + k] = a3;  Bv[(bn0 + 3) * FF + k] = q3;
  } else {
    const int j = k;
    float cbj = b2[j];
    float wc = 0.f;
    for (int kk = 0; kk < FF; ++kk) {
      const float wraw = w2[kk * FF + j];
      const float w = g1[kk] * wraw;
      W2kj[kk * FF + j] = w;
      wc += w;
      cbj = fmaf(be1[kk], wraw, cbj);
    }
    wcol[j] = wc;
    cb[j] = cbj;
    const float gwj = g2[j] * w3[j];
    gw[j] = gwj;
    __shared__ float sA[FF], sB[FF];
    sA[j] = gwj;
    sB[j] = be2[j] * w3[j];
    __syncthreads();
    if (j == 0) {
      float a = 0.f, bq = 0.f;
      for (int i = 0; i < FF; ++i) { a += sA[i]; bq += sB[i]; }
      cwsgw[0] = b3[0] + bq;
      cwsgw[1] = a;
    }
  }
}

// ---------------- main: 256 thr / 256 edges per block, 8 edges x 8 j per lane ----------------
// wave w owns edges [64w, 64w+64) of the block tile; lane <-> edge in phase 1.
// phase 2: lane (eg3 = lane>>3, joct = lane&7) computes local edges 8*eg3..+8, j 8*joct..+8.
__global__ __launch_bounds__(256, 2) void edge_mlp(
    const float* __restrict__ A, const float* __restrict__ Bv,
    const float* __restrict__ W2kj, const float* __restrict__ wcolg,
    const float* __restrict__ cbg, const float* __restrict__ gwg,
    const float* __restrict__ cwsgw,
    const int* __restrict__ bidx, const int* __restrict__ ridx,
    const int* __restrict__ cidx, float* __restrict__ L,
    float4* __restrict__ outv) {
  __shared__ float Wl[FF][FF];       // 16 KB, k-major
  __shared__ float X[4][FF][64];     // 64 KB: [wave][k][edge], k-major

  const int tid = threadIdx.x;       // 0..255
  const int wave = tid >> 6;
  const int lane = tid & 63;

  // fused zeroing of the output grid (1725*256 = 441600 >= OUTV)
  const int gtid = blockIdx.x * 256 + tid;
  if (gtid < OUTV) outv[gtid] = make_float4(0.f, 0.f, 0.f, 0.f);

  // ---- stage W2 (4096 floats = 1024 float4, 4 per thread, coalesced) ----
  {
    const float4* src = (const float4*)W2kj;
    float4* dst = (float4*)&Wl[0][0];
#pragma unroll
    for (int i = 0; i < 4; ++i) dst[tid + 256 * i] = src[tid + 256 * i];
  }

  // ---- phase 1: lane <-> edge; gather ALL 64 k, relu, stats in-register ----
  const int ge = blockIdx.x * TILE_E + tid;
  const int b = bidx[ge], r = ridx[ge], c = cidx[ge];
  float mu, rstd;
  {
    const float4* pa = (const float4*)(A + (b * NN + r) * FF);
    const float4* pb = (const float4*)(Bv + (b * NN + c) * FF);
    float s = 0.f, q = 0.f;
#pragma unroll
    for (int i = 0; i < 16; ++i) {      // 16 float4 = all 64 features (r8 bug: was 8)
      const float4 av = pa[i];
      const float4 bv = pb[i];
      const float x0 = fmaxf(av.x + bv.x, 0.f);
      const float x1 = fmaxf(av.y + bv.y, 0.f);
      const float x2 = fmaxf(av.z + bv.z, 0.f);
      const float x3 = fmaxf(av.w + bv.w, 0.f);
      const int kb = 4 * i;
      X[wave][kb + 0][lane] = x0;   // stride-1 across lanes -> 2-way free
      X[wave][kb + 1][lane] = x1;
      X[wave][kb + 2][lane] = x2;
      X[wave][kb + 3][lane] = x3;
      s += x0; s += x1; s += x2; s += x3;
      q = fmaf(x0, x0, q); q = fmaf(x1, x1, q);
      q = fmaf(x2, x2, q); q = fmaf(x3, x3, q);
    }
    mu = s * (1.f / FF);
    rstd = 1.f / sqrtf(q * (1.f / FF) - mu * mu + 1e-5f);
  }

  __syncthreads();   // covers W staging + all X slabs

  // ---- phase 2: k-loop, 8 edges x 8 j per lane, packed f32x2 ----
  const int joct = lane & 7;
  const int eg3 = lane >> 3;
  f32x2 t2[8][4];
#pragma unroll
  for (int ei = 0; ei < 8; ++ei)
#pragma unroll
    for (int p = 0; p < 4; ++p) t2[ei][p] = (f32x2){0.f, 0.f};

  const float* xrow = &X[wave][0][8 * eg3];   // +64 floats per k
  const float* wrow = &Wl[0][8 * joct];       // +64 floats per k
#pragma unroll 4
  for (int k = 0; k < FF; ++k) {
    const float4 xA = *(const float4*)xrow;
    const float4 xB = *(const float4*)(xrow + 4);
    xrow += 64;
    const float4 wA = *(const float4*)wrow;
    const float4 wB = *(const float4*)(wrow + 4);
    wrow += 64;
    f32x2 w01; w01.x = wA.x; w01.y = wA.y;
    f32x2 w23; w23.x = wA.z; w23.y = wA.w;
    f32x2 w45; w45.x = wB.x; w45.y = wB.y;
    f32x2 w67; w67.x = wB.z; w67.y = wB.w;
    const float xe[8] = {xA.x, xA.y, xA.z, xA.w, xB.x, xB.y, xB.z, xB.w};
#pragma unroll
    for (int ei = 0; ei < 8; ++ei) {
      f32x2 xb; xb.x = xe[ei]; xb.y = xe[ei];
      t2[ei][0] = PKFMA(xb, w01, t2[ei][0]);
      t2[ei][1] = PKFMA(xb, w23, t2[ei][1]);
      t2[ei][2] = PKFMA(xb, w45, t2[ei][2]);
      t2[ei][3] = PKFMA(xb, w67, t2[ei][3]);
    }
  }

  // ---- epilogue: LN1-affine + relu + LN2 stats, reduce over j-octet lanes ----
  float wc[8], cbv[8], gwv[8];
  *(float4*)&wc[0] = *(const float4*)(wcolg + 8 * joct);
  *(float4*)&wc[4] = *(const float4*)(wcolg + 8 * joct + 4);
  *(float4*)&cbv[0] = *(const float4*)(cbg + 8 * joct);
  *(float4*)&cbv[4] = *(const float4*)(cbg + 8 * joct + 4);
  *(float4*)&gwv[0] = *(const float4*)(gwg + 8 * joct);
  *(float4*)&gwv[4] = *(const float4*)(gwg + 8 * joct + 4);
  const float cw = cwsgw[0], sgw = cwsgw[1];

  const int base8 = lane & 56;   // 8*eg3
  float s1[8], s2[8], s3[8];
#pragma unroll
  for (int ei = 0; ei < 8; ++ei) {
    const float m = __shfl(mu, base8 + ei, 64);    // stats of local edge base8+ei
    const float rs = __shfl(rstd, base8 + ei, 64);
    float a1 = 0.f, a2 = 0.f, a3 = 0.f;
#pragma unroll
    for (int jj = 0; jj < 8; ++jj) {
      const float tv = (jj & 1) ? t2[ei][jj >> 1].y : t2[ei][jj >> 1].x;
      const float pre = fmaf(rs, fmaf(-m, wc[jj], tv), cbv[jj]);
      const float tr = fmaxf(pre, 0.f);
      a1 += tr;
      a2 = fmaf(tr, tr, a2);
      a3 = fmaf(tr, gwv[jj], a3);
    }
    s1[ei] = a1; s2[ei] = a2; s3[ei] = a3;
  }
  // butterfly over the j-octet (lane bits 0..2)
#pragma unroll
  for (int off = 1; off <= 4; off <<= 1) {
#pragma unroll
    for (int ei = 0; ei < 8; ++ei) {
      s1[ei] += __shfl_xor(s1[ei], off, 64);
      s2[ei] += __shfl_xor(s2[ei], off, 64);
      s3[ei] += __shfl_xor(s3[ei], off, 64);
    }
  }
  // lane finalizes its OWN edge: base8 + joct == lane (same edge as phase-1 b,r,c)
  const float S1 = sel8(s1, joct);
  const float S2 = sel8(s2, joct);
  const float S3 = sel8(s3, joct);
  const float mu2 = S1 * (1.f / FF);
  const float var2 = S2 * (1.f / FF) - mu2 * mu2;
  const float rstd2 = 1.f / sqrtf(var2 + 1e-5f);
  const float logit = fmaf(rstd2, fmaf(-mu2, sgw, S3), cw);
  L[(b * NSINK + (r - TT)) * NSRC + c] = logit;
}

// ---------------- argmax over sources + scatter ones ----------------
__global__ __launch_bounds__(256) void argmax_scatter(
    const float* __restrict__ L, const float* __restrict__ gum,
    float* __restrict__ out) {
  const int task = blockIdx.x * 4 + (threadIdx.x >> 6);  // ((s*B+b)*192+row)
  const int lane = threadIdx.x & 63;
  const int row = task % NSINK;
  const int sb = task / NSINK;   // s*B + b
  const int b = sb & 7;
  const int r = row + TT;

  const float* __restrict__ lrow = L + (b * NSINK + row) * NSRC;
  const float* __restrict__ grow = gum + task * NSRC;

  float bv = -INFINITY;
  int bi = 0;
  for (int c = lane; c < r; c += 64) {
    const float v = lrow[c] + grow[c];
    if (v > bv) { bv = v; bi = c; }   // strict > keeps smallest index per lane
  }
#pragma unroll
  for (int off = 32; off > 0; off >>= 1) {
    const float ov = __shfl_xor(bv, off, 64);
    const int oi = __shfl_xor(bi, off, 64);
    if (ov > bv || (ov == bv && oi < bi)) { bv = ov; bi = oi; }
  }
  if (lane == 0) out[(b * NN + r) * NN + bi] = 1.0f;
}

extern "C" void kernel_launch(void* const* d_in, const int* in_sizes, int n_in,
                              void* d_out, int out_size, void* d_ws, size_t ws_size,
                              hipStream_t stream) {
  const float* nodes = (const float*)d_in[0];
  const float* w1 = (const float*)d_in[1];
  const float* b1 = (const float*)d_in[2];
  const float* g1 = (const float*)d_in[3];
  const float* be1 = (const float*)d_in[4];
  const float* w2 = (const float*)d_in[5];
  const float* b2 = (const float*)d_in[6];
  const float* g2 = (const float*)d_in[7];
  const float* be2 = (const float*)d_in[8];
  const float* w3 = (const float*)d_in[9];
  const float* b3 = (const float*)d_in[10];
  const float* gum = (const float*)d_in[11];
  const int* bidx = (const int*)d_in[12];
  const int* ridx = (const int*)d_in[13];
  const int* cidx = (const int*)d_in[14];
  float* out = (float*)d_out;

  // workspace layout (floats)
  float* ws = (float*)d_ws;
  float* A = ws;                       // 8*384*64 = 196608
  float* Bv = A + BN * FF;             // 196608
  float* W2kj = Bv + BN * FF;          // 4096
  float* wcol = W2kj + FF * FF;        // 64
  float* cb = wcol + FF;               // 64
  float* gw = cb + FF;                 // 64
  float* cwsgw = gw + FF;              // 2
  float* L = ws + 397520;              // 8*192*383 = 588288
  (void)ws_size; (void)n_in; (void)in_sizes; (void)out_size;

  hipLaunchKernelGGL(prep_all, dim3(BN / 4 + 1), dim3(64), 0, stream,
                     nodes, w1, b1, w2, b2, g1, be1, g2, be2, w3, b3,
                     A, Bv, W2kj, wcol, cb, gw, cwsgw);
  hipLaunchKernelGGL(edge_mlp, dim3(NBLKE), dim3(256), 0, stream,
                     A, Bv, W2kj, wcol, cb, gw, cwsgw, bidx, ridx, cidx, L,
                     (float4*)out);
  hipLaunchKernelGGL(argmax_scatter, dim3((SS * BB * NSINK) / 4), dim3(256), 0, stream,
                     L, gum, out);
}